// Round 1
// 718.711 us; speedup vs baseline: 1.0044x; 1.0044x over previous
//
#include <hip/hip_runtime.h>
#include <stdint.h>

// Problem constants (fixed by setup_inputs): B=1, C=32, Z=64, Y=256, X=256
#define ZS 64
#define CS 32
#define YX 65536          // rays
#define YX4 16384         // YX / 4 (float4 units)
#define RPB 128           // rays per block
#define FAR_DIST 1e10f

// One block = 128 consecutive rays, 256 threads (4 waves). Grid = 512 blocks.
// Phase 1: waves 0-1, one ray per lane: sequential alpha/transmittance chain.
//          noise read directly from global as float4 (64B lines reused across
//          4 z-quads via L1 -> traffic stays ~1x). weights -> w_lds[z][ray].
// Phase 2: thread = (channel-group g = t>>5 of 4 channels, ray-quad q = t&31).
//          feat loads are global_load_dwordx4: 4 rays x 16B per lane, each
//          half-wave reads 512B contiguous. 4x fewer load instrs + addr adds
//          than the scalar-dword version.
__global__ __launch_bounds__(256, 2) void rendernet_kernel(
    const float* __restrict__ feat,   // [C,Z,Y,X]
    const float* __restrict__ occ,    // [Z,Y,X]
    const float* __restrict__ zd,     // [Z]
    const float* __restrict__ noise,  // [N,Z]
    float* __restrict__ out)          // loss(1) + rgb(C*YX) + fe(C*YX) + acc(YX)
{
    __shared__ float w_lds[ZS * RPB];   // 32 KiB, [z][ray]
    __shared__ float dist_s[ZS];

    const int t  = threadIdx.x;
    const int r0 = blockIdx.x * RPB;

    if (t < ZS) {
        float a = zd[t];
        dist_s[t] = (t < ZS - 1) ? (zd[t + 1] - a) : FAR_DIST;
    }
    __syncthreads();

    // ---- Phase 1: weights (sequential over z), thread-per-ray, waves 0-1 ----
    if (t < RPB) {
        const int n = r0 + t;
        const float4* nz4 = reinterpret_cast<const float4*>(noise + (size_t)n * ZS);
        float T = 1.0f, wsum = 0.0f;
        #pragma unroll 4
        for (int zq = 0; zq < ZS / 4; ++zq) {
            float4 nv = nz4[zq];                       // 16B/lane, line reused 4x
            float nsv[4] = {nv.x, nv.y, nv.z, nv.w};
            #pragma unroll
            for (int dz = 0; dz < 4; ++dz) {
                const int z = zq * 4 + dz;
                float o     = occ[(size_t)z * YX + n]; // coalesced across lanes
                float raw   = fmaxf(o + nsv[dz] * 0.1f, 0.0f);
                float alpha = 1.0f - __expf(-raw * dist_s[z]);
                float w     = alpha * T;
                w_lds[z * RPB + t] = w;                // 2-way bank alias: free
                wsum += w;
                T *= (1.0f - alpha + 1e-10f);
            }
        }
        out[(size_t)1 + 2u * (size_t)CS * YX + n] = fminf(fmaxf(wsum, 0.0f), 1.0f);
        if (blockIdx.x == 0 && t == 0) out[0] = 0.0f;  // total_loss
    }
    __syncthreads();

    // ---- Phase 2: feature composite, float4 over rays ----
    const int q  = t & 31;              // ray quad: rays r0 + 4q .. 4q+3
    const int g  = t >> 5;              // channel group: channels 4g .. 4g+3
    const int n0 = r0 + q * 4;

    const float4* f4 = reinterpret_cast<const float4*>(feat);
    // float4 index of feat[c][z][n0] = (c*ZS + z)*YX4 + n0/4
    const size_t base4 = (size_t)(g * 4) * ZS * YX4 + (size_t)(n0 >> 2);

    float4 acc[4];
    #pragma unroll
    for (int j = 0; j < 4; ++j) acc[j] = make_float4(0.f, 0.f, 0.f, 0.f);

    #pragma unroll 4
    for (int z = 0; z < ZS; ++z) {
        const float4 w = *reinterpret_cast<const float4*>(&w_lds[z * RPB + (q << 2)]);
        #pragma unroll
        for (int j = 0; j < 4; ++j) {
            const float4 f = f4[base4 + (size_t)(j * ZS + z) * YX4];  // dwordx4
            acc[j].x += w.x * f.x;
            acc[j].y += w.y * f.y;
            acc[j].z += w.z * f.z;
            acc[j].w += w.w * f.w;
        }
    }

    // out+1 is only 4B-aligned -> scalar stores; 4 consecutive lanes' stores
    // cover each 64B line fully, so L2 write-combining keeps traffic exact.
    float* rgb = out + 1;
    float* fe  = out + 1 + (size_t)CS * YX;
    #pragma unroll
    for (int j = 0; j < 4; ++j) {
        const int c = g * 4 + j;
        const float va[4] = {acc[j].x, acc[j].y, acc[j].z, acc[j].w};
        #pragma unroll
        for (int k = 0; k < 4; ++k) {
            const size_t o = (size_t)c * YX + (size_t)(n0 + k);
            const float v = va[k];
            fe[o]  = v;
            rgb[o] = 1.0f / (1.0f + __expf(-v)) - 0.5f;
        }
    }
}

extern "C" void kernel_launch(void* const* d_in, const int* in_sizes, int n_in,
                              void* d_out, int out_size, void* d_ws, size_t ws_size,
                              hipStream_t stream) {
    const float* feat  = (const float*)d_in[0];
    const float* occ   = (const float*)d_in[1];
    const float* zdist = (const float*)d_in[2];
    const float* noise = (const float*)d_in[3];
    float* out = (float*)d_out;

    rendernet_kernel<<<YX / RPB, 256, 0, stream>>>(feat, occ, zdist, noise, out);
}